// Round 1
// baseline (67.352 us; speedup 1.0000x reference)
//
#include <hip/hip_runtime.h>

// DotInteraction: x [B=8192, N=64, D=128] f32 -> out [B, 2016] f32
// out[b, i*(i-1)/2 + j] = dot(x[b,i,:], x[b,j,:]) for i>j (strict lower tri).
//
// Strategy: 1 wave per batch sample. Whole 64x128 sample lives in registers
// as bf16 MFMA fragments (4 row-blocks x 4 K-chunks x short8 = 64 VGPR).
// Same registers serve as A and B operands of mfma_f32_16x16x32_bf16
// (A row-layout == B col-layout for X·X^T). 10 lower tiles, scatter stores.

#define NFEAT 64
#define FDIM  128
#define NPAIR 2016  // 64*63/2

typedef __attribute__((ext_vector_type(8))) short short8_t;
typedef __attribute__((ext_vector_type(4))) float floatx4;

__device__ __forceinline__ short f2bf(float f) {
    // round-to-nearest-even f32 -> bf16 (inputs are finite; skip NaN path)
    unsigned u = __float_as_uint(f);
    u += 0x7FFFu + ((u >> 16) & 1u);
    return (short)(u >> 16);
}

__global__ __launch_bounds__(256, 4)
void DotInteraction_kernel(const float* __restrict__ x,
                           float* __restrict__ out) {
    const int lane = threadIdx.x & 63;
    const int wid  = threadIdx.x >> 6;
    const int b    = blockIdx.x * 4 + wid;

    const float* __restrict__ xb = x + (size_t)b * (NFEAT * FDIM);

    const int r16 = lane & 15;   // row within 16-block (== col for B operand)
    const int kg  = lane >> 4;   // k-group 0..3 (8 contiguous k each)

    // frag[blk][kc]: lane holds X[blk*16 + r16, kc*32 + kg*8 + 0..7] in bf16
    short8_t frag[4][4];
#pragma unroll
    for (int blk = 0; blk < 4; ++blk) {
#pragma unroll
        for (int kc = 0; kc < 4; ++kc) {
            const float* p = xb + (blk * 16 + r16) * FDIM + kc * 32 + kg * 8;
            floatx4 lo = *reinterpret_cast<const floatx4*>(p);
            floatx4 hi = *reinterpret_cast<const floatx4*>(p + 4);
            short8_t f;
            f[0] = f2bf(lo[0]); f[1] = f2bf(lo[1]);
            f[2] = f2bf(lo[2]); f[3] = f2bf(lo[3]);
            f[4] = f2bf(hi[0]); f[5] = f2bf(hi[1]);
            f[6] = f2bf(hi[2]); f[7] = f2bf(hi[3]);
            frag[blk][kc] = f;
        }
    }

    float* __restrict__ ob = out + (size_t)b * NPAIR;
    const int ci = (lane >> 4) * 4;  // C/D: row = ci + reg, col = lane&15 (m89)
    const int cj = lane & 15;

#pragma unroll
    for (int bi = 0; bi < 4; ++bi) {
#pragma unroll
        for (int bj = 0; bj <= bi; ++bj) {
            floatx4 acc = {0.f, 0.f, 0.f, 0.f};
#pragma unroll
            for (int kc = 0; kc < 4; ++kc) {
                acc = __builtin_amdgcn_mfma_f32_16x16x32_bf16(
                    frag[bi][kc], frag[bj][kc], acc, 0, 0, 0);
            }
#pragma unroll
            for (int r = 0; r < 4; ++r) {
                const int i = bi * 16 + ci + r;
                const int j = bj * 16 + cj;
                if (i > j) {
                    ob[(i * (i - 1)) / 2 + j] = acc[r];
                }
            }
        }
    }
}

extern "C" void kernel_launch(void* const* d_in, const int* in_sizes, int n_in,
                              void* d_out, int out_size, void* d_ws, size_t ws_size,
                              hipStream_t stream) {
    const float* x = (const float*)d_in[0];
    float* out = (float*)d_out;
    // 8192 batches, 1 wave each, 4 waves per 256-thread block -> 2048 blocks
    dim3 grid(2048), block(256);
    hipLaunchKernelGGL(DotInteraction_kernel, grid, block, 0, stream, x, out);
}